// Round 1
// baseline (12787.298 us; speedup 1.0000x reference)
//
#include <hip/hip_runtime.h>
#include <hip/hip_cooperative_groups.h>

namespace cg = cooperative_groups;

#define BB 64      // batch
#define TT 256     // time
#define EE 256     // embed dim
#define NU 1024    // hidden units
#define N3 3072    // 3*NU
#define SCAN_BLOCKS 256
#define UPB 4      // units per scan block

// ---------------------------------------------------------------------------
// Kernel 1: xproj[t*B + b, :] = emb[x[b,t]] @ W + b0      (M=16384,K=256,N=3072)
// 64x64 tile per block, K-chunks of 64, fp32.
// ---------------------------------------------------------------------------
__global__ __launch_bounds__(256) void xproj_kernel(
    const int* __restrict__ x, const float* __restrict__ emb,
    const float* __restrict__ W, const float* __restrict__ bias,
    float* __restrict__ xproj)
{
    __shared__ float AsT[64][68];   // [k][m], padded
    __shared__ float Ws[64][64];    // [k][n]
    __shared__ int   toks[64];

    const int tid = threadIdx.x;
    const int mt = blockIdx.x & 255;   // 256 M-tiles
    const int nt = blockIdx.x >> 8;    // 48 N-tiles
    const int m0 = mt * 64, n0 = nt * 64;

    if (tid < 64) {
        int mg = m0 + tid;            // m' = t*B + b
        int t = mg >> 6, b = mg & 63;
        toks[tid] = x[b * TT + t];
    }
    __syncthreads();

    float acc[4][4] = {};
    const int tx = tid & 15, ty = tid >> 4;

    for (int kb = 0; kb < 4; ++kb) {
        const int k0 = kb * 64;
        if (kb) __syncthreads();
        // stage A (gathered from emb) transposed, and W
        for (int i = 0; i < 4; ++i) {
            int idx = tid + 256 * i;
            int r   = idx >> 4;       // local row (m or k)
            int c4  = idx & 15;       // float4 column
            float4 av = *(const float4*)(emb + (size_t)toks[r] * EE + k0 + c4 * 4);
            AsT[c4 * 4 + 0][r] = av.x;
            AsT[c4 * 4 + 1][r] = av.y;
            AsT[c4 * 4 + 2][r] = av.z;
            AsT[c4 * 4 + 3][r] = av.w;
            *(float4*)&Ws[r][c4 * 4] =
                *(const float4*)(W + (size_t)(k0 + r) * N3 + n0 + c4 * 4);
        }
        __syncthreads();
        #pragma unroll 8
        for (int kk = 0; kk < 64; ++kk) {
            float a[4], w[4];
            *(float4*)a = *(const float4*)&AsT[kk][ty * 4];
            *(float4*)w = *(const float4*)&Ws[kk][tx * 4];
            #pragma unroll
            for (int i = 0; i < 4; ++i)
                #pragma unroll
                for (int j = 0; j < 4; ++j)
                    acc[i][j] += a[i] * w[j];
        }
    }

    float bb4[4];
    *(float4*)bb4 = *(const float4*)(bias + n0 + tx * 4);
    #pragma unroll
    for (int i = 0; i < 4; ++i) {
        float4 o;
        o.x = acc[i][0] + bb4[0];
        o.y = acc[i][1] + bb4[1];
        o.z = acc[i][2] + bb4[2];
        o.w = acc[i][3] + bb4[3];
        *(float4*)(xproj + (size_t)(m0 + ty * 4 + i) * N3 + n0 + tx * 4) = o;
    }
}

// ---------------------------------------------------------------------------
// Kernel 2: persistent cooperative GRU scan.
// 256 blocks x 256 threads; block owns units [u0, u0+4). U-slice LDS-resident.
// hT kept transposed [u][b] in ws, double-buffered; 1 grid.sync per step.
// ---------------------------------------------------------------------------
__global__ __launch_bounds__(256) void gru_scan(
    const int* __restrict__ x, const float* __restrict__ hidden,
    const float* __restrict__ Umat, const float* __restrict__ bias,
    const float* __restrict__ xproj, float* __restrict__ out,
    float* __restrict__ state_out, float* h0buf, float* h1buf)
{
    __shared__ float Us[NU][12];      // 48 KB: U[:, g*NU + u0 + j] at col g*4+j
    __shared__ float hs[256][64];     // 64 KB: chunk of hT (rows=k, cols=b)
    __shared__ float red[256][12];    // 12 KB: k-split partials

    const int tid = threadIdx.x;
    const int bid = blockIdx.x;
    const int u0  = bid * UPB;

    // preload U slice
    for (int idx = tid; idx < NU * 12; idx += 256) {
        int k = idx / 12, c = idx % 12;
        int g = c >> 2, j = c & 3;
        Us[k][c] = Umat[(size_t)k * N3 + g * NU + u0 + j];
    }
    const float* brec = bias + N3;

    // final-compute mapping: thread -> (b, j)
    const int fb = tid >> 2, fj = tid & 3;
    // init hT for our rows
    h0buf[(u0 + fj) * BB + fb] = hidden[fb * NU + u0 + fj];

    // GEMM mapping: wave w handles cols {3w,3w+1,3w+2}; lane = ks*16 + p
    const int w    = tid >> 6;
    const int lane = tid & 63;
    const int ks   = lane >> 4;
    const int p    = lane & 15;

    cg::grid_group grid = cg::this_grid();
    grid.sync();

    float* hc = h0buf;
    float* hn = h1buf;

    for (int t = 0; t < TT; ++t) {
        float acc[4][3] = {};   // [jj over 4 batches][i over 3 cols]
        for (int kb = 0; kb < 4; ++kb) {
            __syncthreads();    // protect hs from previous chunk's readers
            // stage 256 k-rows of hT (contiguous 64 KB)
            const float4* src = (const float4*)(hc + (size_t)kb * 256 * BB);
            float4* dst = (float4*)&hs[0][0];
            #pragma unroll
            for (int i = 0; i < 16; ++i) dst[tid + 256 * i] = src[tid + 256 * i];
            __syncthreads();

            const int kbase = ks * 64;
            const float* urow = &Us[kb * 256 + kbase][0];
            const float* hrow = &hs[kbase][0];
            #pragma unroll 4
            for (int kk = 0; kk < 64; ++kk) {
                float hv[4];
                *(float4*)hv = *(const float4*)(hrow + kk * 64 + p * 4);
                float u0v = urow[kk * 12 + 3 * w + 0];
                float u1v = urow[kk * 12 + 3 * w + 1];
                float u2v = urow[kk * 12 + 3 * w + 2];
                #pragma unroll
                for (int jj = 0; jj < 4; ++jj) {
                    acc[jj][0] += hv[jj] * u0v;
                    acc[jj][1] += hv[jj] * u1v;
                    acc[jj][2] += hv[jj] * u2v;
                }
            }
        }
        __syncthreads();
        #pragma unroll
        for (int jj = 0; jj < 4; ++jj)
            #pragma unroll
            for (int i = 0; i < 3; ++i) red[tid][jj * 3 + i] = acc[jj][i];
        __syncthreads();

        // final: thread (fb, fj) computes unit u0+fj for batch fb
        float rec[3];
        #pragma unroll
        for (int g = 0; g < 3; ++g) {
            int c = g * 4 + fj;
            int wr = c / 3, ir = c % 3;
            float s = 0.f;
            #pragma unroll
            for (int kss = 0; kss < 4; ++kss)
                s += red[wr * 64 + kss * 16 + (fb >> 2)][(fb & 3) * 3 + ir];
            rec[g] = s + brec[g * NU + u0 + fj];
        }
        size_t xpo = ((size_t)t * BB + fb) * N3 + u0 + fj;
        float xz = xproj[xpo];
        float xr = xproj[xpo + NU];
        float xh = xproj[xpo + 2 * NU];
        float hold = hc[(u0 + fj) * BB + fb];

        float z  = 1.f / (1.f + expf(-(xz + rec[0])));
        float r  = 1.f / (1.f + expf(-(xr + rec[1])));
        float hh = tanhf(xh + r * rec[2]);
        float hnew = z * hold + (1.f - z) * hh;
        if (x[fb * TT + t] == 0) hnew = hold;   // mask_zero: carry state

        hn[(u0 + fj) * BB + fb] = hnew;
        out[((size_t)fb * TT + t) * NU + u0 + fj] = hnew;
        if (t == TT - 1) state_out[fb * NU + u0 + fj] = hnew;

        grid.sync();
        float* tmp = hc; hc = hn; hn = tmp;
    }
}

// ---------------------------------------------------------------------------
extern "C" void kernel_launch(void* const* d_in, const int* in_sizes, int n_in,
                              void* d_out, int out_size, void* d_ws, size_t ws_size,
                              hipStream_t stream) {
    const int*   x      = (const int*)d_in[0];
    const float* hidden = (const float*)d_in[1];
    const float* emb    = (const float*)d_in[2];
    const float* W      = (const float*)d_in[3];
    const float* U      = (const float*)d_in[4];
    const float* bvec   = (const float*)d_in[5];

    float* out   = (float*)d_out;
    float* state = out + (size_t)BB * TT * NU;

    float* xproj = (float*)d_ws;
    float* h0    = (float*)((char*)d_ws + (size_t)BB * TT * N3 * sizeof(float));
    float* h1    = h0 + BB * NU;

    xproj_kernel<<<dim3(256 * 48), dim3(256), 0, stream>>>(x, emb, W, bvec, xproj);

    void* args[] = {(void*)&x, (void*)&hidden, (void*)&U, (void*)&bvec,
                    (void*)&xproj, (void*)&out, (void*)&state,
                    (void*)&h0, (void*)&h1};
    hipLaunchCooperativeKernel((const void*)gru_scan, dim3(SCAN_BLOCKS), dim3(256),
                               args, 0, stream);
}